// Round 7
// baseline (132.892 us; speedup 1.0000x reference)
//
#include <hip/hip_runtime.h>

#define BB 128
#define LL 336
#define CC 862
#define PRED 96
#define WIN 12
#define S_IN 28
#define S_OUT 8
#define NQ 7                      // s chunks of 4
#define CT 32
#define NTILES ((CC + CT - 1) / CT)   // 27

#define SQRT12F 3.4641016151377544f

// -Sb(t)/sqrt(12), Sb(t) = 2*sum_{k=1..5} sin(pi*k*t/6)   (exact closed forms)
__device__ const float COEFP[12] = {
    0.0f, -2.1547005383792515f, 0.0f, -0.5773502691896258f,
    0.0f, -0.15470053837925146f, 0.0f, 0.15470053837925146f,
    0.0f,  0.5773502691896258f, 0.0f,  2.1547005383792515f
};

// ---- prep kernels ----

// repacked layout: wX4[((q*S_OUT + p)*CC + c)*4 + j]  = wX[c][p][4q+j]
__global__ void prep_w4(const float* __restrict__ wA, const float* __restrict__ wP,
                        float* __restrict__ wA4, float* __restrict__ wP4) {
    int i = blockIdx.x * 256 + threadIdx.x;
    if (i >= NQ * S_OUT * CC * 4) return;
    int j  = i & 3;
    int c  = (i >> 2) % CC;
    int p  = (i / (4 * CC)) % S_OUT;
    int q  = i / (4 * CC * S_OUT);
    int s  = 4 * q + j;
    int src = (c * S_OUT + p) * S_IN + s;
    wA4[i] = wA[src];
    wP4[i] = wP[src];
}

__global__ void prep_mcoef(const float* __restrict__ wA, float* __restrict__ mcoefT) {
    int i = blockIdx.x * 256 + threadIdx.x;          // [p][c]
    if (i >= S_OUT * CC) return;
    int c = i % CC;
    int p = i / CC;
    float s = 0.f;
    for (int k = 0; k < S_IN; ++k) s += wA[(c * S_OUT + p) * S_IN + k];
    mcoefT[i] = 1.0f - s;
}

__global__ void prep_bias(const float* __restrict__ bA, const float* __restrict__ bP,
                          float* __restrict__ biasv) {
    int i = blockIdx.x * 256 + threadIdx.x;          // [t][p][c]
    if (i >= 12 * S_OUT * CC) return;
    int c = i % CC;
    int tp = i / CC;
    int p = tp % S_OUT;
    int t = tp / S_OUT;
    float v = COEFP[t] * bP[c * S_OUT + p];
    if (t == 0) v += SQRT12F * bA[c * S_OUT + p];
    biasv[i] = v;
}

// ---- fused main kernel: ALL 56 x loads issued up front (max MLP),
//      per-p write-out (only 2 accumulators live), weights via L2 float4 ----
// thread = (cc 0..31, pair 0..7); pairs 0..6 active; t=pair, tr=(12-t)%12

template <bool TRANS>
__global__ __launch_bounds__(256, 4) void fused7(
    const float* __restrict__ x,
    const float* __restrict__ wA4, const float* __restrict__ wP4,
    const float* __restrict__ mcoefT, const float* __restrict__ biasv,
    const float* __restrict__ wA_raw, const float* __restrict__ wP_raw,
    const float* __restrict__ bAr, const float* __restrict__ bPr,
    float* __restrict__ out)
{
    __shared__ float ssum[7][CT];    // 896 B

    const int b    = blockIdx.y;
    const int c0   = blockIdx.x * CT;
    const int NC   = min(CT, CC - c0);
    const int tid  = threadIdx.x;
    const int cc   = tid & 31;
    const int pair = tid >> 5;          // 0..7
    const int c    = c0 + cc;
    const int cl   = (c < CC) ? c : (CC - 1);   // clamped for loads
    const int t    = (pair < 7) ? pair : 0;
    const int tr   = (12 - t) % 12;
    const bool active = (pair < 7) && (cc < NC);

    // ---- phase 1: all 56 x loads, fully independent ----
    float xt[S_IN], xr[S_IN];
    const float* pt = x + ((size_t)b * LL + t)  * CC + cl;
    const float* pr = x + ((size_t)b * LL + tr) * CC + cl;
    #pragma unroll
    for (int s = 0; s < S_IN; ++s) {
        xt[s] = pt[(size_t)(s * WIN) * CC];
        xr[s] = pr[(size_t)(s * WIN) * CC];
    }

    // u/v in place: xt -> u, xr -> v
    float su = 0.f;
    #pragma unroll
    for (int s = 0; s < S_IN; ++s) {
        const float a = xt[s], r = xr[s];
        xt[s] = a + r;
        xr[s] = a - r;
        su += xt[s];
    }

    // per-channel mean from pair u-sums
    if (pair < 7) {
        ssum[pair][cc] = (t == 0 || t == 6) ? 0.5f * su : su;
    }
    __syncthreads();
    float mean = 0.f;
    #pragma unroll
    for (int r = 0; r < 7; ++r) mean += ssum[r][cc];
    mean *= (1.0f / LL);

    if (!active) return;

    float* ob = out + ((size_t)b * PRED) * CC + c;

    // ---- phase 2: per-p dot products; write out immediately ----
    #pragma unroll 1
    for (int p = 0; p < S_OUT; ++p) {
        float A = 0.f, P = 0.f, mc, bias_t, bias_r;
        if (TRANS) {
            const float4* wa4 = reinterpret_cast<const float4*>(wA4) + (size_t)p * CC + cl;
            const float4* wp4 = reinterpret_cast<const float4*>(wP4) + (size_t)p * CC + cl;
            #pragma unroll
            for (int q = 0; q < NQ; ++q) {
                const float4 wa = wa4[(size_t)(q * S_OUT) * CC];
                const float4 wp = wp4[(size_t)(q * S_OUT) * CC];
                A = fmaf(wa.x, xt[4*q+0], A);
                A = fmaf(wa.y, xt[4*q+1], A);
                A = fmaf(wa.z, xt[4*q+2], A);
                A = fmaf(wa.w, xt[4*q+3], A);
                P = fmaf(wp.x, xr[4*q+0], P);
                P = fmaf(wp.y, xr[4*q+1], P);
                P = fmaf(wp.z, xr[4*q+2], P);
                P = fmaf(wp.w, xr[4*q+3], P);
            }
            mc     = mcoefT[p * CC + c];
            bias_t = biasv[(t  * S_OUT + p) * CC + c];
            bias_r = biasv[(tr * S_OUT + p) * CC + c];
        } else {
            const float* wa = wA_raw + (size_t)(c * S_OUT + p) * S_IN;
            const float* wp = wP_raw + (size_t)(c * S_OUT + p) * S_IN;
            float sw = 0.f;
            #pragma unroll
            for (int s = 0; s < S_IN; ++s) {
                const float was = wa[s];
                A = fmaf(was, xt[s], A);
                P = fmaf(wp[s], xr[s], P);
                sw += was;
            }
            mc = 1.0f - sw;
            const float ba = bAr[c * S_OUT + p], bp = bPr[c * S_OUT + p];
            bias_t = COEFP[t]  * bp + (t == 0 ? SQRT12F * ba : 0.f);
            bias_r = COEFP[tr] * bp;
        }
        const float mb = mean * mc;
        ob[(size_t)(p * WIN + t) * CC] = 0.5f * (A + P) + mb + bias_t;
        if (t != tr) {
            ob[(size_t)(p * WIN + tr) * CC] = 0.5f * (A - P) + mb + bias_r;
        }
    }
}

extern "C" void kernel_launch(void* const* d_in, const int* in_sizes, int n_in,
                              void* d_out, int out_size, void* d_ws, size_t ws_size,
                              hipStream_t stream) {
    const float* x  = (const float*)d_in[0];
    const float* wA = (const float*)d_in[1];
    const float* bA = (const float*)d_in[2];
    const float* wP = (const float*)d_in[3];
    const float* bP = (const float*)d_in[4];
    float* out = (float*)d_out;

    const size_t nW  = (size_t)NQ * S_OUT * CC * 4;  // 193088
    const size_t nM  = (size_t)S_OUT * CC;           // 6896
    const size_t nBv = (size_t)12 * S_OUT * CC;      // 82752
    const size_t need = (2 * nW + nM + nBv) * sizeof(float);

    dim3 grid(NTILES, BB);

    if (ws_size >= need) {
        float* wA4    = (float*)d_ws;
        float* wP4    = wA4 + nW;
        float* mcoefT = wP4 + nW;
        float* biasv  = mcoefT + nM;

        prep_w4<<<(int)((nW + 255) / 256), 256, 0, stream>>>(wA, wP, wA4, wP4);
        prep_mcoef<<<(int)((nM + 255) / 256), 256, 0, stream>>>(wA, mcoefT);
        prep_bias<<<(int)((nBv + 255) / 256), 256, 0, stream>>>(bA, bP, biasv);

        fused7<true><<<grid, 256, 0, stream>>>(
            x, wA4, wP4, mcoefT, biasv,
            nullptr, nullptr, nullptr, nullptr, out);
    } else {
        fused7<false><<<grid, 256, 0, stream>>>(
            x, nullptr, nullptr, nullptr, nullptr,
            wA, wP, bA, bP, out);
    }
}